// Round 4
// baseline (323.129 us; speedup 1.0000x reference)
//
#include <hip/hip_runtime.h>

// B = 2097152 rows x 25 f32 (pre, tar).
// loss = mean_b [ mean_24 ( (3*softmax4(pre[b,:24]) - tar[b,:24])^2 ) ]
//
// R1-R3: three different schedules (barriers/no barriers, occ 27-55%, DMA vs
// VGPR staging) all land 82-84us -> bytes-delivered wall (~6 TB/s, m13 ceiling)
// for the main kernel (~70us) + ~10us fixed overhead (2nd launch + node gap).
// R4: fuse final reduction (threadfence + atomic counter, last block reduces,
//     bit-deterministic), zero-tail grid (4096 x 1-wave blocks, 8 tiles each,
//     all resident), keep LDS-transpose structure.

constexpr int B_ROWS   = 2097152;
constexpr int ROWW     = 25;
constexpr int WTILE    = 64;                     // rows per tile = lanes
constexpr int NTHREADS = 64;                     // one wave per block
constexpr int NBLOCKS  = 4096;
constexpr int NTILES   = B_ROWS / WTILE;         // 32768
constexpr int TPB      = NTILES / NBLOCKS;       // 8 tiles per block, exact
constexpr int TILE_F4  = WTILE * ROWW / 4;       // 400 float4

__global__ __launch_bounds__(NTHREADS)
void soft_add_fused(const float* __restrict__ pre,
                    const float* __restrict__ tar,
                    float* __restrict__ out,
                    float* __restrict__ partial,
                    unsigned int* __restrict__ counter)
{
    __shared__ float s_pre[WTILE * ROWW];        // 6400 B
    const int lane = threadIdx.x;
    const int bid  = blockIdx.x;

    float acc = 0.0f;

    for (int k = 0; k < TPB; ++k) {
        const long t = (long)bid * TPB + k;
        const long base = t * (WTILE * ROWW);    // 16B-aligned (6400B tiles)
        const float4* gp = reinterpret_cast<const float4*>(pre + base);
        const float4* gt = reinterpret_cast<const float4*>(tar + base);
        float4* sp = reinterpret_cast<float4*>(s_pre);

        // coalesced loads: tar -> regs (stays live through softmax),
        // pre -> regs -> LDS (transposer)
        float4 rt[7], rp[7];
        #pragma unroll
        for (int j = 0; j < 7; ++j) {
            const int i = lane + j * 64;
            if (j < 6 || lane < 16) rt[j] = gt[i];
        }
        #pragma unroll
        for (int j = 0; j < 7; ++j) {
            const int i = lane + j * 64;
            if (j < 6 || lane < 16) rp[j] = gp[i];
        }
        #pragma unroll
        for (int j = 0; j < 7; ++j) {
            const int i = lane + j * 64;
            if (j < 6 || lane < 16) sp[i] = rp[j];
        }
        __syncthreads();   // 1-wave block: ~free (waitcnt-level)

        // softmax: lane owns row `lane`; stride-25 b32 reads = conflict-free
        float* rowp = s_pre + lane * ROWW;
        float o[24];
        #pragma unroll
        for (int g = 0; g < 6; ++g) {
            const float v0 = rowp[4*g + 0];
            const float v1 = rowp[4*g + 1];
            const float v2 = rowp[4*g + 2];
            const float v3 = rowp[4*g + 3];
            const float m  = fmaxf(fmaxf(v0, v1), fmaxf(v2, v3));
            const float e0 = __expf(v0 - m);
            const float e1 = __expf(v1 - m);
            const float e2 = __expf(v2 - m);
            const float e3 = __expf(v3 - m);
            const float r  = 3.0f / (e0 + e1 + e2 + e3);
            o[4*g + 0] = e0 * r;
            o[4*g + 1] = e1 * r;
            o[4*g + 2] = e2 * r;
            o[4*g + 3] = e3 * r;
        }
        #pragma unroll
        for (int m2 = 0; m2 < 24; ++m2) rowp[m2] = o[m2];
        __syncthreads();

        // diff: coalesced float4 LDS re-read vs tar regs, mask col 24
        #pragma unroll
        for (int j = 0; j < 7; ++j) {
            const int i = lane + j * 64;
            if (j < 6 || lane < 16) {
                const float4 ov = sp[i];
                const float4 tv = rt[j];
                int col = (4 * i) % 25;
                float d;
                d = ov.x - tv.x; if (col != 24) acc += d * d; col = (col == 24) ? 0 : col + 1;
                d = ov.y - tv.y; if (col != 24) acc += d * d; col = (col == 24) ? 0 : col + 1;
                d = ov.z - tv.z; if (col != 24) acc += d * d; col = (col == 24) ? 0 : col + 1;
                d = ov.w - tv.w; if (col != 24) acc += d * d;
            }
        }
        __syncthreads();   // before next tile overwrites s_pre
    }

    // wave reduce (fixed tree -> deterministic)
    #pragma unroll
    for (int off = 32; off > 0; off >>= 1)
        acc += __shfl_down(acc, off, 64);

    // last-block-done final reduction (bit-deterministic: fixed array, fixed order)
    unsigned int prev = 0;
    if (lane == 0) {
        partial[bid] = acc;
        __threadfence();                          // release partials device-wide
        prev = atomicAdd(counter, 1u);
    }
    prev = __shfl(prev, 0, 64);
    if (prev == NBLOCKS - 1) {
        __threadfence();                          // acquire others' partials
        float s = 0.0f;
        for (int i = lane; i < NBLOCKS; i += 64)
            s += partial[i];
        #pragma unroll
        for (int off = 32; off > 0; off >>= 1)
            s += __shfl_down(s, off, 64);
        if (lane == 0)
            out[0] = s * (1.0f / (24.0f * (float)B_ROWS));
    }
}

extern "C" void kernel_launch(void* const* d_in, const int* in_sizes, int n_in,
                              void* d_out, int out_size, void* d_ws, size_t ws_size,
                              hipStream_t stream)
{
    const float* pre = (const float*)d_in[0];
    const float* tar = (const float*)d_in[1];
    float* out = (float*)d_out;
    float* partial = (float*)d_ws;                               // 16 KB
    unsigned int* counter = (unsigned int*)((char*)d_ws + NBLOCKS * sizeof(float));

    hipMemsetAsync(counter, 0, sizeof(unsigned int), stream);    // capture-safe
    soft_add_fused<<<NBLOCKS, NTHREADS, 0, stream>>>(pre, tar, out, partial, counter);
}

// Round 5
// 175.331 us; speedup vs baseline: 1.8430x; 1.8430x over previous
//
#include <hip/hip_runtime.h>

// B = 2097152 rows x 25 f32 (pre, tar).
// loss = mean_b [ mean_24 ( (3*softmax4(pre[b,:24]) - tar[b,:24])^2 ) ]
//
// R1-R3: three schedules (barriers / no barriers, occ 27-55%, DMA vs VGPR
// staging) all 82-84us -> delivered-bytes wall (~5.5 TB/s mixed HBM+L3).
// R4: 1-wave blocks spilled rt/rp/o to scratch (WRITE_SIZE 205MB) -> 323us.
// R5: exact R2 kernel (proven 83.8us, VGPR 40, no spill) + ONLY change:
//     fused last-block final reduction (atomic counter, deterministic order)
//     to remove the 2nd dispatch + graph node gap.

constexpr int B_ROWS    = 2097152;
constexpr int ROWW      = 25;                    // floats per row
constexpr int TILE_ROWS = 256;
constexpr int NTHREADS  = 256;
constexpr int NBLOCKS   = 2048;
constexpr int NTILES    = B_ROWS / TILE_ROWS;    // 8192
constexpr int TILE_F4   = TILE_ROWS * ROWW / 4;  // 1600 float4 per array
constexpr int F4_PER_T  = (TILE_F4 + NTHREADS - 1) / NTHREADS;  // 7 (last partial)

__global__ __launch_bounds__(NTHREADS)
void soft_add_fused(const float* __restrict__ pre,
                    const float* __restrict__ tar,
                    float* __restrict__ out,
                    float* __restrict__ partial,
                    unsigned int* __restrict__ counter)
{
    __shared__ float s_pre[TILE_ROWS * ROWW];    // 25600 B
    __shared__ float s_red[NTHREADS / 64];

    const int tid = threadIdx.x;
    float acc = 0.0f;

    for (int tile = blockIdx.x; tile < NTILES; tile += gridDim.x) {
        const long base = (long)tile * TILE_ROWS * ROWW;  // 16B-aligned (256*100B)
        const float4* gp = reinterpret_cast<const float4*>(pre + base);
        const float4* gt = reinterpret_cast<const float4*>(tar + base);
        float4* sp = reinterpret_cast<float4*>(s_pre);

        // 1) tar -> registers (coalesced, live through softmax phase)
        float4 rt[F4_PER_T];
        #pragma unroll
        for (int j = 0; j < F4_PER_T; ++j) {
            const int i = tid + j * NTHREADS;
            if (i < TILE_F4) rt[j] = gt[i];
        }
        // 2) pre -> LDS (coalesced)
        #pragma unroll
        for (int j = 0; j < F4_PER_T; ++j) {
            const int i = tid + j * NTHREADS;
            if (i < TILE_F4) sp[i] = gp[i];
        }
        __syncthreads();

        // 3) softmax in-place: thread t owns row t (stride 25 -> conflict-free)
        float* rp = s_pre + tid * ROWW;
        #pragma unroll
        for (int g = 0; g < 6; ++g) {
            const float v0 = rp[4*g + 0];
            const float v1 = rp[4*g + 1];
            const float v2 = rp[4*g + 2];
            const float v3 = rp[4*g + 3];
            const float m  = fmaxf(fmaxf(v0, v1), fmaxf(v2, v3));
            const float e0 = __expf(v0 - m);
            const float e1 = __expf(v1 - m);
            const float e2 = __expf(v2 - m);
            const float e3 = __expf(v3 - m);
            const float r  = 3.0f / (e0 + e1 + e2 + e3);
            rp[4*g + 0] = e0 * r;
            rp[4*g + 1] = e1 * r;
            rp[4*g + 2] = e2 * r;
            rp[4*g + 3] = e3 * r;
        }
        __syncthreads();

        // 4) diff: registers (tar) vs LDS (out), skipping col 24
        #pragma unroll
        for (int j = 0; j < F4_PER_T; ++j) {
            const int i = tid + j * NTHREADS;
            if (i < TILE_F4) {
                const float4 o = sp[i];
                const float4 t = rt[j];
                int col = (4 * i) % 25;
                float d;
                d = o.x - t.x; if (col != 24) acc += d * d; col = (col == 24) ? 0 : col + 1;
                d = o.y - t.y; if (col != 24) acc += d * d; col = (col == 24) ? 0 : col + 1;
                d = o.z - t.z; if (col != 24) acc += d * d; col = (col == 24) ? 0 : col + 1;
                d = o.w - t.w; if (col != 24) acc += d * d;
            }
        }
        __syncthreads();   // before next tile overwrites s_pre
    }

    // wave64 butterfly reduce, then cross-wave via LDS (fixed order)
    #pragma unroll
    for (int off = 32; off > 0; off >>= 1)
        acc += __shfl_down(acc, off, 64);
    const int wave = tid >> 6;
    const int lane = tid & 63;
    if (lane == 0) s_red[wave] = acc;
    __syncthreads();

    // last-block-done final reduction (deterministic: fixed array, fixed tree)
    __shared__ unsigned int s_prev;
    if (tid == 0) {
        float s = 0.0f;
        #pragma unroll
        for (int w = 0; w < NTHREADS / 64; ++w) s += s_red[w];
        partial[blockIdx.x] = s;
        __threadfence();                          // release partial device-wide
        s_prev = atomicAdd(counter, 1u);
    }
    __syncthreads();
    if (s_prev == NBLOCKS - 1) {
        __threadfence();                          // acquire others' partials
        float s = 0.0f;
        #pragma unroll
        for (int r = 0; r < NBLOCKS / NTHREADS; ++r)
            s += partial[tid + r * NTHREADS];
        #pragma unroll
        for (int off = 32; off > 0; off >>= 1)
            s += __shfl_down(s, off, 64);
        if (lane == 0) s_red[wave] = s;
        __syncthreads();
        if (tid == 0) {
            float t = 0.0f;
            #pragma unroll
            for (int w = 0; w < NTHREADS / 64; ++w) t += s_red[w];
            out[0] = t * (1.0f / (24.0f * (float)B_ROWS));
        }
    }
}

extern "C" void kernel_launch(void* const* d_in, const int* in_sizes, int n_in,
                              void* d_out, int out_size, void* d_ws, size_t ws_size,
                              hipStream_t stream)
{
    const float* pre = (const float*)d_in[0];
    const float* tar = (const float*)d_in[1];
    float* out = (float*)d_out;
    float* partial = (float*)d_ws;                               // 8 KB
    unsigned int* counter = (unsigned int*)((char*)d_ws + NBLOCKS * sizeof(float));

    hipMemsetAsync(counter, 0, sizeof(unsigned int), stream);    // capture-safe
    soft_add_fused<<<NBLOCKS, NTHREADS, 0, stream>>>(pre, tar, out, partial, counter);
}

// Round 6
// 79.961 us; speedup vs baseline: 4.0411x; 2.1927x over previous
//
#include <hip/hip_runtime.h>

// B = 2097152 rows x 25 f32 (pre, tar).
// loss = mean_b [ mean_24 ( (3*softmax4(pre[b,:24]) - tar[b,:24])^2 ) ]
//
// R1-R3: three schedules (barriers / no barriers, occ 27-55%, DMA vs VGPR
// staging) all land 82-84us -> delivered-bytes wall (419 MB @ ~5.5 TB/s
// mixed HBM+L3; FETCH_SIZE pinned at 205 MB in every variant).
// R4: 1-wave fused version spilled to scratch (WRITE_SIZE 205 MB) -> 323us.
// R5: fused last-block reduction: threadfence (buffer_wbl2/inv walk) + 2048
//     same-address atomics -> +90us pure stall at identical traffic -> 175us.
// R6: pure revert to the R3 champion (81.8us): per-wave private
//     double-buffered tiles, global_load_lds staging, counted vmcnt(14),
//     zero barriers in the main loop, separate 1-block final-reduce kernel.

constexpr int B_ROWS   = 2097152;
constexpr int ROWW     = 25;
constexpr int WTILE    = 64;                   // rows per wave-tile
constexpr int WT_FLOAT = WTILE * ROWW;         // 1600 floats = 6400 B
constexpr int NTHREADS = 256;                  // 4 waves
constexpr int WAVES_PB = NTHREADS / 64;
constexpr int NBLOCKS  = 2048;
constexpr int NWAVES   = NBLOCKS * WAVES_PB;   // 8192 waves
constexpr int NWTILES  = B_ROWS / WTILE;       // 32768 wave-tiles
constexpr int NITER    = NWTILES / NWAVES;     // 4 tiles per wave

// Stage one 6400B wave-tile into LDS: 6 x (64 lanes x 16B) + 1 x (64 lanes x 4B).
// LDS dest is wave-uniform base + lane*size (HW rule), global src is per-lane.
#define DMA_TILE(GSRC, LBUF) do {                                              \
    _Pragma("unroll")                                                          \
    for (int c = 0; c < 6; ++c) {                                              \
        const float* g_ = (GSRC) + c * 256 + lane * 4;                         \
        __builtin_amdgcn_global_load_lds(                                      \
            (const __attribute__((address_space(1))) void*)g_,                 \
            (__attribute__((address_space(3))) void*)((LBUF) + c * 256),       \
            16, 0, 0);                                                         \
    }                                                                          \
    const float* gt_ = (GSRC) + 1536 + lane;                                   \
    __builtin_amdgcn_global_load_lds(                                          \
        (const __attribute__((address_space(1))) void*)gt_,                    \
        (__attribute__((address_space(3))) void*)((LBUF) + 1536),              \
        4, 0, 0);                                                              \
} while (0)

// 7 coalesced float4 loads of one wave-tile of tar into a register array.
#define LOAD_TAR(RT, GBASE) do {                                               \
    const float4* gt4_ = reinterpret_cast<const float4*>(GBASE);               \
    _Pragma("unroll")                                                          \
    for (int j = 0; j < 7; ++j) {                                              \
        const int i_ = lane + j * 64;                                          \
        if (j < 6 || lane < 16) (RT)[j] = gt4_[i_];                            \
    }                                                                          \
} while (0)

// Row-space softmax from LDS (stride-25 b32: conflict-free),
// in-place writeback, lgkm fence, coalesced b128 re-read, diff vs tar regs.
#define COMPUTE_TILE(BUF, RT) do {                                             \
    const float* rowp_ = (BUF) + lane * ROWW;                                  \
    float o_[24];                                                              \
    _Pragma("unroll")                                                          \
    for (int g6 = 0; g6 < 6; ++g6) {                                           \
        const float v0 = rowp_[4*g6 + 0];                                      \
        const float v1 = rowp_[4*g6 + 1];                                      \
        const float v2 = rowp_[4*g6 + 2];                                      \
        const float v3 = rowp_[4*g6 + 3];                                      \
        const float m_ = fmaxf(fmaxf(v0, v1), fmaxf(v2, v3));                  \
        const float e0 = __expf(v0 - m_);                                      \
        const float e1 = __expf(v1 - m_);                                      \
        const float e2 = __expf(v2 - m_);                                      \
        const float e3 = __expf(v3 - m_);                                      \
        const float r_ = 3.0f / (e0 + e1 + e2 + e3);                           \
        o_[4*g6 + 0] = e0 * r_;                                                \
        o_[4*g6 + 1] = e1 * r_;                                                \
        o_[4*g6 + 2] = e2 * r_;                                                \
        o_[4*g6 + 3] = e3 * r_;                                                \
    }                                                                          \
    float* roww_ = (BUF) + lane * ROWW;                                        \
    _Pragma("unroll")                                                          \
    for (int m2 = 0; m2 < 24; ++m2) roww_[m2] = o_[m2];                        \
    asm volatile("s_waitcnt lgkmcnt(0)" ::: "memory");                         \
    __builtin_amdgcn_sched_barrier(0);                                         \
    const float4* bf4_ = reinterpret_cast<const float4*>(BUF);                 \
    _Pragma("unroll")                                                          \
    for (int j = 0; j < 7; ++j) {                                              \
        const int i_ = lane + j * 64;                                          \
        if (j < 6 || lane < 16) {                                              \
            const float4 ov = bf4_[i_];                                        \
            const float4 tv = (RT)[j];                                         \
            int col_ = (4 * i_) % 25;                                          \
            float d_;                                                          \
            d_ = ov.x - tv.x; if (col_ != 24) acc += d_ * d_;                  \
            col_ = (col_ == 24) ? 0 : col_ + 1;                                \
            d_ = ov.y - tv.y; if (col_ != 24) acc += d_ * d_;                  \
            col_ = (col_ == 24) ? 0 : col_ + 1;                                \
            d_ = ov.z - tv.z; if (col_ != 24) acc += d_ * d_;                  \
            col_ = (col_ == 24) ? 0 : col_ + 1;                                \
            d_ = ov.w - tv.w; if (col_ != 24) acc += d_ * d_;                  \
        }                                                                      \
    }                                                                          \
} while (0)

#define WAIT_VM14() do {                                                       \
    asm volatile("s_waitcnt vmcnt(14)" ::: "memory");                          \
    __builtin_amdgcn_sched_barrier(0);                                         \
} while (0)
#define WAIT_VM0() do {                                                        \
    asm volatile("s_waitcnt vmcnt(0)" ::: "memory");                           \
    __builtin_amdgcn_sched_barrier(0);                                         \
} while (0)

__global__ __launch_bounds__(NTHREADS)
void soft_add_partial(const float* __restrict__ pre,
                      const float* __restrict__ tar,
                      float* __restrict__ partial)
{
    __shared__ float lds[WAVES_PB][2][WT_FLOAT];   // 51200 B
    __shared__ float s_red[WAVES_PB];

    const int tid  = threadIdx.x;
    const int lane = tid & 63;
    const int wv   = tid >> 6;
    const int gw   = blockIdx.x * WAVES_PB + wv;   // global wave id, 0..8191

    float* buf0 = &lds[wv][0][0];
    float* buf1 = &lds[wv][1][0];

    // tile k lives at float offset (gw + k*NWAVES) * WT_FLOAT
    const float* p0 = pre + (long)(gw + 0 * NWAVES) * WT_FLOAT;
    const float* p1 = pre + (long)(gw + 1 * NWAVES) * WT_FLOAT;
    const float* p2 = pre + (long)(gw + 2 * NWAVES) * WT_FLOAT;
    const float* p3 = pre + (long)(gw + 3 * NWAVES) * WT_FLOAT;
    const float* t0 = tar + (long)(gw + 0 * NWAVES) * WT_FLOAT;
    const float* t1 = tar + (long)(gw + 1 * NWAVES) * WT_FLOAT;
    const float* t2 = tar + (long)(gw + 2 * NWAVES) * WT_FLOAT;
    const float* t3 = tar + (long)(gw + 3 * NWAVES) * WT_FLOAT;

    float acc = 0.0f;
    float4 rtA[7], rtB[7];

    // prologue: tile 0 in flight
    DMA_TILE(p0, buf0);
    LOAD_TAR(rtA, t0);

    // k=0: prefetch tile1, wait tile0, compute tile0
    DMA_TILE(p1, buf1);
    LOAD_TAR(rtB, t1);
    WAIT_VM14();
    COMPUTE_TILE(buf0, rtA);

    // k=1: prefetch tile2 (into buf0: its reads above are consumed), compute tile1
    DMA_TILE(p2, buf0);
    LOAD_TAR(rtA, t2);
    WAIT_VM14();
    COMPUTE_TILE(buf1, rtB);

    // k=2: prefetch tile3, compute tile2
    DMA_TILE(p3, buf1);
    LOAD_TAR(rtB, t3);
    WAIT_VM14();
    COMPUTE_TILE(buf0, rtA);

    // k=3: drain, compute tile3
    WAIT_VM0();
    COMPUTE_TILE(buf1, rtB);

    // block reduction (single barrier at the very end)
    #pragma unroll
    for (int off = 32; off > 0; off >>= 1)
        acc += __shfl_down(acc, off, 64);
    if (lane == 0) s_red[wv] = acc;
    __syncthreads();
    if (tid == 0) {
        float s = 0.0f;
        #pragma unroll
        for (int w = 0; w < WAVES_PB; ++w) s += s_red[w];
        partial[blockIdx.x] = s;
    }
}

__global__ __launch_bounds__(NTHREADS)
void soft_add_final(const float* __restrict__ partial, float* __restrict__ out)
{
    __shared__ float s_red[NTHREADS / 64];
    const int tid = threadIdx.x;
    float acc = 0.0f;
    for (int i = tid; i < NBLOCKS; i += NTHREADS)
        acc += partial[i];
    #pragma unroll
    for (int off = 32; off > 0; off >>= 1)
        acc += __shfl_down(acc, off, 64);
    const int wave = tid >> 6;
    const int lane = tid & 63;
    if (lane == 0) s_red[wave] = acc;
    __syncthreads();
    if (tid == 0) {
        float s = 0.0f;
        #pragma unroll
        for (int w = 0; w < NTHREADS / 64; ++w) s += s_red[w];
        out[0] = s * (1.0f / (24.0f * (float)B_ROWS));
    }
}

extern "C" void kernel_launch(void* const* d_in, const int* in_sizes, int n_in,
                              void* d_out, int out_size, void* d_ws, size_t ws_size,
                              hipStream_t stream)
{
    const float* pre = (const float*)d_in[0];
    const float* tar = (const float*)d_in[1];
    float* out = (float*)d_out;
    float* partial = (float*)d_ws;   // NBLOCKS*4 = 8 KB

    soft_add_partial<<<NBLOCKS, NTHREADS, 0, stream>>>(pre, tar, partial);
    soft_add_final<<<1, NTHREADS, 0, stream>>>(partial, out);
}